// Round 8
// baseline (41.745 us; speedup 1.0000x reference)
//
#include <hip/hip_runtime.h>
#include <hip/hip_bf16.h>

typedef __attribute__((ext_vector_type(8))) float float8;

// Bit-exact emulation of the Cephes float32 log family (numpy SIMD / XLA /
// Eigen all use these coefficients and the 0.693359375 / -2.12194440e-4 split).
// Serial FMA Horner. At xa = 2^m (the divide-fork points) ALL variants agree
// bit-exactly since the reduced x is 0 and the polynomial vanishes.
__device__ __forceinline__ float np_logf(float xin) {
  union { float f; unsigned u; } v; v.f = xin;
  int e = (int)(v.u >> 23) - 126;               // xin = m * 2^e, m in [0.5,1)
  v.u = (v.u & 0x007fffffu) | 0x3f000000u;
  float m = v.f;
  if (m < 0.70710678118654752440f) { e -= 1; m = m + m; }  // exact
  m = m - 1.0f;                                  // exact (Sterbenz)
  float p = 7.0376836292e-2f;
  p = fmaf(p, m, -1.1514610310e-1f);
  p = fmaf(p, m,  1.1676998740e-1f);
  p = fmaf(p, m, -1.2420140846e-1f);
  p = fmaf(p, m,  1.4249322787e-1f);
  p = fmaf(p, m, -1.6668057665e-1f);
  p = fmaf(p, m,  2.0000714765e-1f);
  p = fmaf(p, m, -2.4999993993e-1f);
  p = fmaf(p, m,  3.3333331174e-1f);
  float z = m * m;
  float y = (p * m) * z;                         // ((P(x)*x)*x^2)
  float fe = (float)e;
  y = fmaf(fe, -2.12194440e-4f, y);
  y = fmaf(-0.5f, z, y);
  float r = m + y;
  r = fmaf(fe, 0.693359375f, r);
  return r;
}

// out[b,i,j] = pos_w[j-i+N-1] + ts_w[clip(bucket(ts[b,min(i+1,N-1)]-ts[b,j]),0,NB)]
// bucket(d) = floorf( np_logf(max(|d|,1)) / 0.6931471824645996f )  -- ALL f32:
// divisor = RN32(ln 2) = 0x3F317218 (what jnp.log(2.0) / f32-np.log(2.0) give).
__global__ __launch_bounds__(256) void bias_kernel(
    const int* __restrict__ ts, const float* __restrict__ ts_w,
    const float* __restrict__ pos_w,
    float* __restrict__ out, int N, int NB1) {
  __shared__ float sW[512];
  const int tid = threadIdx.x;
  for (int k = tid; k < NB1 && k < 512; k += 256) sW[k] = ts_w[k];
  __syncthreads();

  const int i = blockIdx.x;   // output row
  const int b = blockIdx.y;   // batch
  const int NBUCK = NB1 - 1;

  const int* tsrow = ts + (size_t)b * N;            // int32 timestamps
  const int tip1 = tsrow[min(i + 1, N - 1)];        // ext[:,1:], last elem repeated
  const float* pw = pos_w + (N - 1 - i);            // pw[j] = pos_w[j - i + N - 1]

  for (int j0 = tid * 8; j0 < N; j0 += 256 * 8) {
    int4 ta = *reinterpret_cast<const int4*>(tsrow + j0);
    int4 tb = *reinterpret_cast<const int4*>(tsrow + j0 + 4);
    int tv[8] = {ta.x, ta.y, ta.z, ta.w, tb.x, tb.y, tb.z, tb.w};

    float8 st;
#pragma unroll
    for (int e = 0; e < 8; ++e) {
      int d = tip1 - tv[e];
      unsigned xa = (unsigned)(d < 0 ? -d : d);
      xa |= (unsigned)(xa == 0);                    // max(|d|, 1), < 2^24
      float lx = np_logf((float)xa);                // exact int->f32 (<2^24)
      float q = lx / 0.6931471824645996f;           // f32 divide (no promotion!)
      int bb = (int)floorf(q);                      // f32 floor
      bb = min(max(bb, 0), NBUCK);                  // clip(0, NUM_BUCKETS)
      st[e] = pw[j0 + e] + sW[bb];                  // exact f32 sum
    }
    *reinterpret_cast<float8*>(out + ((size_t)b * N + i) * N + j0) = st;  // f32 out
  }
}

extern "C" void kernel_launch(void* const* d_in, const int* in_sizes, int n_in,
                              void* d_out, int out_size, void* d_ws, size_t ws_size,
                              hipStream_t stream) {
  // Identify inputs BY SIZE (robust to ordering):
  //   timestamps = largest (B*N), ts_w = smallest (NBUCK+1), pos_w = middle (2N-1).
  int i_ts = 0;
  if (in_sizes[1] > in_sizes[i_ts]) i_ts = 1;
  if (in_sizes[2] > in_sizes[i_ts]) i_ts = 2;
  int i_tsw = 0;
  if (in_sizes[1] < in_sizes[i_tsw]) i_tsw = 1;
  if (in_sizes[2] < in_sizes[i_tsw]) i_tsw = 2;
  int i_pw = 3 - i_ts - i_tsw;

  const int* ts = (const int*)d_in[i_ts];          // int32 on device
  const float* ts_w = (const float*)d_in[i_tsw];   // f32 (R3 NaN proof)
  const float* pos_w = (const float*)d_in[i_pw];

  const int NB1 = in_sizes[i_tsw];           // NUM_BUCKETS + 1
  const int N = (in_sizes[i_pw] + 1) / 2;    // pos_w has 2N-1
  const int B = in_sizes[i_ts] / N;

  dim3 grid(N, B);
  bias_kernel<<<grid, 256, 0, stream>>>(ts, ts_w, pos_w,
                                        (float*)d_out, N, NB1);
}